// Round 8
// baseline (250.826 us; speedup 1.0000x reference)
//
#include <hip/hip_runtime.h>

typedef short bf16x8 __attribute__((ext_vector_type(8)));
typedef float f32x4 __attribute__((ext_vector_type(4)));
typedef float f32x16 __attribute__((ext_vector_type(16)));

__device__ __forceinline__ ushort f2bf(float f) {
    union { float f; unsigned u; } v; v.f = f;
    unsigned r = (v.u + 0x7fffu + ((v.u >> 16) & 1u)) >> 16;
    return (ushort)r;
}
__device__ __forceinline__ float bf2f(ushort u) {
    union { unsigned u; float f; } v; v.u = ((unsigned)u) << 16;
    return v.f;
}
__device__ __forceinline__ void async_copy16(void* lds, const void* g) {
    __builtin_amdgcn_global_load_lds(
        (const __attribute__((address_space(1))) unsigned*)g,
        (__attribute__((address_space(3))) unsigned*)lds, 16, 0, 0);
}
// Barrier that waits only LDS ops — leaves global/vmcnt prefetches in flight.
__device__ __forceinline__ void lds_barrier() {
    asm volatile("s_waitcnt lgkmcnt(0)\n\ts_barrier" ::: "memory");
}

// ---------------- fused prep: cvt_x | cvt_wT(Wq,Wk) | cvt(Wv) | compact ------
__global__ __launch_bounds__(256)
void prep_kernel(const float* __restrict__ x, const float* __restrict__ Wq,
                 const float* __restrict__ Wk, const float* __restrict__ Wv,
                 const int* __restrict__ mask,
                 ushort* __restrict__ xb, ushort* __restrict__ wqT,
                 ushort* __restrict__ wkT, ushort* __restrict__ wvb,
                 int* __restrict__ idx, int* __restrict__ cnt)
{
    const int bid = blockIdx.x, t = threadIdx.x;
    if (bid < 8192) {                       // x fp32 -> bf16
        int i = (bid * 256 + t) * 4;
        float4 v = *(const float4*)(x + i);
        ushort4 o;
        o.x = f2bf(v.x); o.y = f2bf(v.y); o.z = f2bf(v.z); o.w = f2bf(v.w);
        *(ushort4*)(xb + i) = o;
    } else if (bid < 8320) {                // Wq/Wk transpose-convert
        __shared__ ushort T[64][72];
        int r = bid - 8192;
        const int z = r >> 6; r &= 63;
        const float* in = z ? Wk : Wq;
        ushort* out     = z ? wkT : wqT;
        const int r0 = (r >> 3) * 64, c0 = (r & 7) * 64;
        const int rr = t >> 3, cc8 = (t & 7) * 8;
        #pragma unroll
        for (int pass = 0; pass < 2; ++pass) {
            int rw = rr + pass * 32;
            float4 a = *(const float4*)(in + (size_t)(r0 + rw) * 512 + c0 + cc8);
            float4 bq = *(const float4*)(in + (size_t)(r0 + rw) * 512 + c0 + cc8 + 4);
            T[rw][cc8+0]=f2bf(a.x);  T[rw][cc8+1]=f2bf(a.y);  T[rw][cc8+2]=f2bf(a.z);  T[rw][cc8+3]=f2bf(a.w);
            T[rw][cc8+4]=f2bf(bq.x); T[rw][cc8+5]=f2bf(bq.y); T[rw][cc8+6]=f2bf(bq.z); T[rw][cc8+7]=f2bf(bq.w);
        }
        __syncthreads();
        const int c = t >> 2, seg = (t & 3) * 16;
        ushort tmp[16];
        #pragma unroll
        for (int j = 0; j < 16; ++j) tmp[j] = T[seg + j][c];
        *(uint4*)(out + (size_t)(c0 + c) * 512 + r0 + seg)     = *(uint4*)&tmp[0];
        *(uint4*)(out + (size_t)(c0 + c) * 512 + r0 + seg + 8) = *(uint4*)&tmp[8];
    } else if (bid < 8576) {                // Wv fp32 -> bf16
        int i = ((bid - 8320) * 256 + t) * 4;
        float4 v = *(const float4*)(Wv + i);
        ushort4 o;
        o.x = f2bf(v.x); o.y = f2bf(v.y); o.z = f2bf(v.z); o.w = f2bf(v.w);
        *(ushort4*)(wvb + i) = o;
    } else {                                // mask compaction
        __shared__ int sc[256];
        int seg = bid - 8576, b = seg >> 1, half = seg & 1;
        const int* m = mask + b * 2048 + half * 1024;
        int v0 = (m[t*4+0] == 0), v1 = (m[t*4+1] == 0);
        int v2 = (m[t*4+2] == 0), v3 = (m[t*4+3] == 0);
        int c = v0 + v1 + v2 + v3;
        sc[t] = c; __syncthreads();
        for (int ofs = 1; ofs < 256; ofs <<= 1) {
            int xx = (t >= ofs) ? sc[t - ofs] : 0;
            __syncthreads(); sc[t] += xx; __syncthreads();
        }
        int pos = sc[t] - c + seg * 1024;
        if (v0) idx[pos++] = t*4+0;
        if (v1) idx[pos++] = t*4+1;
        if (v2) idx[pos++] = t*4+2;
        if (v3) idx[pos++] = t*4+3;
        if (t == 255) cnt[seg] = sc[255];
    }
}

// --------- row translation: compacted key-row -> absolute xb row -------------
__device__ __forceinline__ int map_row(const int* __restrict__ idx,
                                       const int* __restrict__ cnt, int row) {
    int seg = row >> 10, j = row & 1023;
    int src = (j < cnt[seg]) ? idx[(seg << 10) + j] : 0;
    return (seg << 10) + src;
}

// ---------------- shared GEMM core: C[m][n] = sum_k A[m][k]*B[n][k] ----------
// mapA/mapB: translate operand rows through idx/cnt (on-the-fly gather).
// vt=1: write V-fragment-tiled layout [seg][kt32][db16][g2][dr32][k16]
//   (seg=n>>10, key=n&1023 -> kt32=key>>5, g2=(key>>4)&1, k=key&15;
//    db=m>>5, dr=m&31) — verified end-to-end in R4.
__device__ __forceinline__ void gemm_core(const ushort* __restrict__ A,
                                          const ushort* __restrict__ B,
                                          ushort* __restrict__ C,
                                          int N, int K, int mBase, int nBase,
                                          int mapA, int mapB,
                                          const int* __restrict__ idx,
                                          const int* __restrict__ cnt,
                                          int vt)
{
    __shared__ ushort As[128][32];
    __shared__ ushort Bs[128][32];
    const int tid = threadIdx.x;
    const int lane = tid & 63, wave = tid >> 6;
    const int wm = wave >> 1, wn = wave & 1;
    const int lr = lane & 15, lq = lane >> 4;
    const int sr = lane >> 2;
    const int sc = (lane & 3) * 8;

    // Per-thread staging source pointers (fixed across the K loop).
    const ushort* aptr[2];
    const ushort* bptr[2];
    #pragma unroll
    for (int j = 0; j < 2; ++j) {
        int ra = mBase + wave * 32 + j * 16 + sr;
        int rb = nBase + wave * 32 + j * 16 + sr;
        int sa = mapA ? map_row(idx, cnt, ra) : ra;
        int sb = mapB ? map_row(idx, cnt, rb) : rb;
        aptr[j] = A + (size_t)sa * K + sc;
        bptr[j] = B + (size_t)sb * K + sc;
    }

    f32x4 acc[4][4];
    #pragma unroll
    for (int i = 0; i < 4; ++i)
        #pragma unroll
        for (int j = 0; j < 4; ++j) acc[i][j] = (f32x4){0.f, 0.f, 0.f, 0.f};

    for (int k0 = 0; k0 < K; k0 += 32) {
        __syncthreads();
        #pragma unroll
        for (int j = 0; j < 2; ++j) {
            int rbase = wave * 32 + j * 16;
            async_copy16(&As[rbase][0], aptr[j] + k0);
            async_copy16(&Bs[rbase][0], bptr[j] + k0);
        }
        __syncthreads();
        bf16x8 af[4], bfr[4];
        #pragma unroll
        for (int mi = 0; mi < 4; ++mi) af[mi] = *(const bf16x8*)&As[wm * 64 + mi * 16 + lr][lq * 8];
        #pragma unroll
        for (int ni = 0; ni < 4; ++ni) bfr[ni] = *(const bf16x8*)&Bs[wn * 64 + ni * 16 + lr][lq * 8];
        #pragma unroll
        for (int mi = 0; mi < 4; ++mi)
            #pragma unroll
            for (int ni = 0; ni < 4; ++ni)
                acc[mi][ni] = __builtin_amdgcn_mfma_f32_16x16x32_bf16(af[mi], bfr[ni], acc[mi][ni], 0, 0, 0);
    }
    #pragma unroll
    for (int mi = 0; mi < 4; ++mi)
        #pragma unroll
        for (int ni = 0; ni < 4; ++ni)
            #pragma unroll
            for (int r = 0; r < 4; ++r) {
                int m = mBase + wm * 64 + mi * 16 + lq * 4 + r;
                int n = nBase + wn * 64 + ni * 16 + lr;
                float val = acc[mi][ni][r];
                if (!vt) {
                    C[(size_t)m * N + n] = f2bf(val);
                } else {
                    int sseg = n >> 10, key = n & 1023;
                    size_t ix = (size_t)sseg * 524288 + (size_t)(key >> 5) * 16384
                              + (size_t)(m >> 5) * 1024 + ((key >> 4) & 1) * 512
                              + (m & 31) * 16 + (key & 15);
                    C[ix] = f2bf(val);
                }
            }
}

__global__ __launch_bounds__(256, 2)
void gemm_m(const ushort* __restrict__ A, const ushort* __restrict__ B,
            ushort* __restrict__ C) {
    gemm_core(A, B, C, 512, 512, blockIdx.y * 128, blockIdx.x * 128,
              0, 0, nullptr, nullptr, 0);
}

// fused K' and Vt gemms (z-decode); both skip all-pad 128-bands and gather
// compacted rows from xb via idx on the fly. Vt written fragment-tiled.
__global__ __launch_bounds__(256, 2)
void gemm_kv(const ushort* __restrict__ xb, const ushort* __restrict__ Mb,
             ushort* __restrict__ Kc, const ushort* __restrict__ wv,
             ushort* __restrict__ Vtc, const int* __restrict__ idx,
             const int* __restrict__ cnt)
{
    if (blockIdx.z == 0) {
        int mBase = blockIdx.y * 128, nBase = blockIdx.x * 128;
        if ((mBase & 1023) >= cnt[mBase >> 10]) return;
        gemm_core(xb, Mb, Kc, 512, 512, mBase, nBase, 1, 0, idx, cnt, 0);
    } else {
        int mBase = blockIdx.x * 128, nBase = blockIdx.y * 128;
        if ((nBase & 1023) >= cnt[nBase >> 10]) return;
        gemm_core(wv, xb, Vtc, 16384, 512, mBase, nBase, 0, 1, idx, cnt, 1);
    }
}

// ---------------- flash attention over COMPACTED keys ------------------------
// Q = xb [B*S][512] bf16. K'c: [16][1024][512] (linear). Vt frag-tiled:
// [16][kt32][db16][g2][dr32][k16]. K staged in LDS via global_load_lds
// (issued AFTER the PV loop so PV's V-load vmcnt waits never queue behind it
// — vmcnt completes in order; R4's bug was the reverse order). V fragments
// read DIRECTLY from L2/L1-resident tiled global (XCD swizzle pins the
// segment; 32KB V-tile fits L1) — removes the V LDS round-trip that was 40%
// of the measured LDS-pipe bound and all 2.19M bank conflicts.
__global__ __launch_bounds__(256, 2)
void attn_kernel(const ushort* __restrict__ Qg, const ushort* __restrict__ Kcg,
                 const ushort* __restrict__ Vtcg, const int* __restrict__ cntg,
                 ushort* __restrict__ Pog, float* __restrict__ Mlg)
{
    const int S = 2048;
    const float SL2E = 0.0637587160f;  // (1/sqrt(512)) * log2(e)

    __shared__ ushort Ks[32][548];
    __shared__ ushort Ps[2][32][36];

    // XCD swizzle: all 32 q-tiles of a segment on one XCD (2 segs/XCD).
    const int lin = blockIdx.x + 32 * blockIdx.y + 256 * blockIdx.z;
    const int seg = (lin & 7) * 2 + (lin >> 8);
    const int qt  = (lin >> 3) & 31;
    const int b = seg >> 1, half = seg & 1;

    const int tid = threadIdx.x, lane = tid & 63, wave = tid >> 6;
    const int lr = lane & 15, lq = lane >> 4;
    const int p = wave >> 1, s = wave & 1;
    const int l32 = lane & 31, lh = lane >> 5;

    const int n = cntg[seg];
    const int ntiles = (n + 31) >> 5;

    const ushort* Qp = Qg + ((size_t)b * S + qt * 64 + wave * 16 + lr) * 512;
    bf16x8 qf[16];
    #pragma unroll
    for (int c = 0; c < 16; ++c) qf[c] = *(const bf16x8*)(Qp + c * 32 + lq * 8);

    f32x16 o[8];
    #pragma unroll
    for (int i = 0; i < 8; ++i)
        #pragma unroll
        for (int r = 0; r < 16; ++r) o[i][r] = 0.f;
    float l_i[4] = {0.f, 0.f, 0.f, 0.f};

    const char* Kseg = (const char*)(Kcg + (size_t)seg * 1024 * 512);
    const ushort* Vseg = Vtcg + (size_t)seg * 524288;

    // Prologue: issue K(0) -> Ks (async, 8 rows per wave).
    {
        #pragma unroll
        for (int i = 0; i < 8; ++i) {
            int row = wave * 8 + i;
            async_copy16(&Ks[row][0], Kseg + (size_t)row * 1024 + lane * 16);
        }
    }

    for (int kt = 0; kt < ntiles; ++kt) {
        const int key0 = kt * 32;
        // Top barrier: drains vmcnt(0) -> Ks(kt) landed; Ps free.
        __syncthreads();
        const bool va0 = (key0 + lr) < n;
        const bool va1 = (key0 + 16 + lr) < n;
        // QK^T: 4 independent accumulator chains for MFMA-latency slack.
        f32x4 sA = (f32x4){0.f,0.f,0.f,0.f}, sB = (f32x4){0.f,0.f,0.f,0.f};
        f32x4 sC = (f32x4){0.f,0.f,0.f,0.f}, sD = (f32x4){0.f,0.f,0.f,0.f};
        __builtin_amdgcn_s_setprio(1);
        #pragma unroll
        for (int ks = 0; ks < 16; ks += 2) {
            bf16x8 kf0a = *(const bf16x8*)&Ks[lr][ks * 32 + lq * 8];
            bf16x8 kf1a = *(const bf16x8*)&Ks[16 + lr][ks * 32 + lq * 8];
            bf16x8 kf0b = *(const bf16x8*)&Ks[lr][(ks + 1) * 32 + lq * 8];
            bf16x8 kf1b = *(const bf16x8*)&Ks[16 + lr][(ks + 1) * 32 + lq * 8];
            sA = __builtin_amdgcn_mfma_f32_16x16x32_bf16(qf[ks], kf0a, sA, 0, 0, 0);
            sB = __builtin_amdgcn_mfma_f32_16x16x32_bf16(qf[ks], kf1a, sB, 0, 0, 0);
            sC = __builtin_amdgcn_mfma_f32_16x16x32_bf16(qf[ks + 1], kf0b, sC, 0, 0, 0);
            sD = __builtin_amdgcn_mfma_f32_16x16x32_bf16(qf[ks + 1], kf1b, sD, 0, 0, 0);
        }
        __builtin_amdgcn_s_setprio(0);
        #pragma unroll
        for (int r = 0; r < 4; ++r) {
            float s0 = sA[r] + sC[r], s1 = sB[r] + sD[r];
            float p0 = va0 ? exp2f(fmaf(s0, SL2E, -8.f)) : 0.f;
            float p1 = va1 ? exp2f(fmaf(s1, SL2E, -8.f)) : 0.f;
            l_i[r] += p0 + p1;
            Ps[p][16 * s + lq * 4 + r][lr]      = f2bf(p0);
            Ps[p][16 * s + lq * 4 + r][16 + lr] = f2bf(p1);
        }
        // Mid barrier (lgkm only): Ps visible; Ks dead (all QK reads done).
        lds_barrier();
        bf16x8 pA0 = *(const bf16x8*)&Ps[p][l32][lh * 8];
        bf16x8 pA1 = *(const bf16x8*)&Ps[p][l32][16 + lh * 8];
        // PV: B-frags streamed from L2/L1 (frag-tiled Vt). These loads are
        // OLDER than any K-stage op (issued below) -> never wait on K.
        const ushort* Vt = Vseg + (size_t)kt * 16384 + l32 * 16 + lh * 8;
        __builtin_amdgcn_s_setprio(1);
        #pragma unroll
        for (int dt = 0; dt < 8; ++dt) {
            const int db = s * 8 + dt;
            bf16x8 v0 = *(const bf16x8*)(Vt + db * 1024);
            bf16x8 v1 = *(const bf16x8*)(Vt + db * 1024 + 512);
            o[dt] = __builtin_amdgcn_mfma_f32_32x32x16_bf16(pA0, v0, o[dt], 0, 0, 0);
            o[dt] = __builtin_amdgcn_mfma_f32_32x32x16_bf16(pA1, v1, o[dt], 0, 0, 0);
        }
        __builtin_amdgcn_s_setprio(0);
        // Issue K(kt+1) after PV: exposed at the next top barrier (R0-proven
        // free — the two resident blocks interleave across it).
        if (kt + 1 < ntiles) {
            const char* gK = Kseg + (size_t)(key0 + 32) * 1024;
            #pragma unroll
            for (int i = 0; i < 8; ++i) {
                int row = wave * 8 + i;
                async_copy16(&Ks[row][0], gK + (size_t)row * 1024 + lane * 16);
            }
        }
    }
    #pragma unroll
    for (int r = 0; r < 4; ++r)
        #pragma unroll
        for (int off = 1; off < 16; off <<= 1)
            l_i[r] += __shfl_xor(l_i[r], off, 16);
    const size_t growbase = (size_t)half * 16384 + (size_t)b * S + qt * 64;
    if (lr == 0) {
        #pragma unroll
        for (int r = 0; r < 4; ++r)
            Mlg[growbase + wave * 16 + lq * 4 + r] = l_i[r];
    }
    ushort* Pop = Pog + (growbase + p * 32) * 512;
    #pragma unroll
    for (int dt = 0; dt < 8; ++dt) {
        int ocol = s * 256 + dt * 32 + l32;
        #pragma unroll
        for (int r = 0; r < 16; ++r) {
            int orow = (r & 3) + 8 * (r >> 2) + 4 * lh;
            Pop[(size_t)orow * 512 + ocol] = f2bf(o[dt][r]);
        }
    }
}

// ---------------- combine the two key-halves ----------------
__global__ __launch_bounds__(256)
void combine_kernel(const ushort* __restrict__ Po, const float* __restrict__ Ml,
                    float* __restrict__ out)
{
    int i = (blockIdx.x * 256 + threadIdx.x) * 4;
    int row = i >> 9;
    float l = Ml[row] + Ml[16384 + row];
    float s = l > 0.f ? 1.f / l : 0.f;
    ushort4 p1 = *(const ushort4*)(Po + i);
    ushort4 p2 = *(const ushort4*)(Po + 8388608 + i);
    float4 o;
    o.x = (bf2f(p1.x) + bf2f(p2.x)) * s;
    o.y = (bf2f(p1.y) + bf2f(p2.y)) * s;
    o.z = (bf2f(p1.z) + bf2f(p2.z)) * s;
    o.w = (bf2f(p1.w) + bf2f(p2.w)) * s;
    *(float4*)(out + i) = o;
}

extern "C" void kernel_launch(void* const* d_in, const int* in_sizes, int n_in,
                              void* d_out, int out_size, void* d_ws, size_t ws_size,
                              hipStream_t stream) {
    const float* x  = (const float*)d_in[0];
    // d_in[1] = bias: additive scalar on all logits -> softmax shift-invariant -> no-op
    const int* mask = (const int*)d_in[2];
    const float* Wq = (const float*)d_in[3];
    const float* Wk = (const float*)d_in[4];
    const float* Wv = (const float*)d_in[5];
    float* out = (float*)d_out;

    // Workspace (ushort units). Vtc region holds the fragment-tiled V layout.
    ushort* ws   = (ushort*)d_ws;
    ushort* xb   = ws;
    ushort* wqT  = ws + 8388608;
    ushort* wkT  = wqT + 262144;
    ushort* wvb  = wkT + 262144;
    ushort* Pob  = ws + 9175040;
    ushort* Mb   = ws + 17563648;
    int*    idxb = (int*)(ws + 17825792);
    ushort* Kc   = ws + 25952256;
    ushort* Vtc  = ws + 34340864;
    float*  Mlb  = (float*)(ws + 42729472);
    int*    cntb = (int*)(ws + 42795008);

    prep_kernel<<<8592, 256, 0, stream>>>(x, Wq, Wk, Wv, mask,
                                          xb, wqT, wkT, wvb, idxb, cntb);
    // M = Wq^T Wk
    gemm_m<<<dim3(4, 4), 256, 0, stream>>>(wqT, wkT, Mb);
    // K'c = gather(xb) M^T  and  Vt(frag-tiled) = Wv gather(xb)^T
    gemm_kv<<<dim3(4, 128, 2), 256, 0, stream>>>(xb, Mb, Kc, wvb, Vtc, idxb, cntb);
    attn_kernel<<<dim3(32, 8, 2), 256, 0, stream>>>(xb, Kc, Vtc, cntb, Pob, Mlb);
    combine_kernel<<<8192, 256, 0, stream>>>(Pob, Mlb, out);
}

// Round 9
// 236.780 us; speedup vs baseline: 1.0593x; 1.0593x over previous
//
#include <hip/hip_runtime.h>

typedef short bf16x8 __attribute__((ext_vector_type(8)));
typedef float f32x4 __attribute__((ext_vector_type(4)));
typedef float f32x16 __attribute__((ext_vector_type(16)));
typedef ushort u16x8 __attribute__((ext_vector_type(8)));

__device__ __forceinline__ ushort f2bf(float f) {
    union { float f; unsigned u; } v; v.f = f;
    unsigned r = (v.u + 0x7fffu + ((v.u >> 16) & 1u)) >> 16;
    return (ushort)r;
}
__device__ __forceinline__ float bf2f(ushort u) {
    union { unsigned u; float f; } v; v.u = ((unsigned)u) << 16;
    return v.f;
}
__device__ __forceinline__ void async_copy16(void* lds, const void* g) {
    __builtin_amdgcn_global_load_lds(
        (const __attribute__((address_space(1))) unsigned*)g,
        (__attribute__((address_space(3))) unsigned*)lds, 16, 0, 0);
}
// Barrier that waits only LDS ops — leaves global/vmcnt prefetches in flight.
__device__ __forceinline__ void lds_barrier() {
    asm volatile("s_waitcnt lgkmcnt(0)\n\ts_barrier" ::: "memory");
}

// ------- fused prep: cvt_x | M = Wq^T Wk (direct fp32) | cvt(Wv) | compact ---
// grid 8480: [0,8192) cvt x; [8192,8208) M-gemm from raw fp32 Wq/Wk
// (transpose-convert staging, overlapped with the memory-bound x pass —
// replaces the separate 16-block gemm_m launch that serialized ~10us of
// near-idle GPU); [8208,8464) cvt Wv; [8464,8480) mask compaction.
__global__ __launch_bounds__(256)
void prep_kernel(const float* __restrict__ x, const float* __restrict__ Wq,
                 const float* __restrict__ Wk, const float* __restrict__ Wv,
                 const int* __restrict__ mask,
                 ushort* __restrict__ xb, ushort* __restrict__ wvb,
                 ushort* __restrict__ Mb,
                 int* __restrict__ idx, int* __restrict__ cnt)
{
    const int bid = blockIdx.x, t = threadIdx.x;
    if (bid < 8192) {                       // x fp32 -> bf16
        int i = (bid * 256 + t) * 4;
        float4 v = *(const float4*)(x + i);
        ushort4 o;
        o.x = f2bf(v.x); o.y = f2bf(v.y); o.z = f2bf(v.z); o.w = f2bf(v.w);
        *(ushort4*)(xb + i) = o;
    } else if (bid < 8208) {                // M[m][n] = sum_k Wq[k][m] Wk[k][n]
        __shared__ ushort As[128][32];
        __shared__ ushort Bs[128][32];
        const int bb = bid - 8192;
        const int m0 = (bb >> 2) * 128, n0 = (bb & 3) * 128;
        const int lane = t & 63, wave = t >> 6;
        const int wm = wave >> 1, wn = wave & 1;
        const int lr = lane & 15, lq = lane >> 4;
        const int kk = t >> 3, mm = (t & 7) * 16;

        f32x4 acc[4][4];
        #pragma unroll
        for (int i2 = 0; i2 < 4; ++i2)
            #pragma unroll
            for (int j2 = 0; j2 < 4; ++j2) acc[i2][j2] = (f32x4){0.f,0.f,0.f,0.f};

        for (int k0 = 0; k0 < 512; k0 += 32) {
            float4 qa[4], kb[4];
            #pragma unroll
            for (int j = 0; j < 4; ++j) {
                qa[j] = *(const float4*)(Wq + (size_t)(k0 + kk) * 512 + m0 + mm + j * 4);
                kb[j] = *(const float4*)(Wk + (size_t)(k0 + kk) * 512 + n0 + mm + j * 4);
            }
            __syncthreads();   // previous iter's fragment reads done (WAR)
            #pragma unroll
            for (int j = 0; j < 4; ++j) {
                As[mm + j*4 + 0][kk] = f2bf(qa[j].x);
                As[mm + j*4 + 1][kk] = f2bf(qa[j].y);
                As[mm + j*4 + 2][kk] = f2bf(qa[j].z);
                As[mm + j*4 + 3][kk] = f2bf(qa[j].w);
                Bs[mm + j*4 + 0][kk] = f2bf(kb[j].x);
                Bs[mm + j*4 + 1][kk] = f2bf(kb[j].y);
                Bs[mm + j*4 + 2][kk] = f2bf(kb[j].z);
                Bs[mm + j*4 + 3][kk] = f2bf(kb[j].w);
            }
            __syncthreads();   // staging visible (RAW)
            bf16x8 af[4], bfr[4];
            #pragma unroll
            for (int mi = 0; mi < 4; ++mi) af[mi]  = *(const bf16x8*)&As[wm * 64 + mi * 16 + lr][lq * 8];
            #pragma unroll
            for (int ni = 0; ni < 4; ++ni) bfr[ni] = *(const bf16x8*)&Bs[wn * 64 + ni * 16 + lr][lq * 8];
            #pragma unroll
            for (int mi = 0; mi < 4; ++mi)
                #pragma unroll
                for (int ni = 0; ni < 4; ++ni)
                    acc[mi][ni] = __builtin_amdgcn_mfma_f32_16x16x32_bf16(af[mi], bfr[ni], acc[mi][ni], 0, 0, 0);
        }
        #pragma unroll
        for (int mi = 0; mi < 4; ++mi)
            #pragma unroll
            for (int ni = 0; ni < 4; ++ni)
                #pragma unroll
                for (int r = 0; r < 4; ++r) {
                    int m = m0 + wm * 64 + mi * 16 + lq * 4 + r;
                    int n = n0 + wn * 64 + ni * 16 + lr;
                    Mb[(size_t)m * 512 + n] = f2bf(acc[mi][ni][r]);
                }
    } else if (bid < 8464) {                // Wv fp32 -> bf16
        int i = ((bid - 8208) * 256 + t) * 4;
        float4 v = *(const float4*)(Wv + i);
        ushort4 o;
        o.x = f2bf(v.x); o.y = f2bf(v.y); o.z = f2bf(v.z); o.w = f2bf(v.w);
        *(ushort4*)(wvb + i) = o;
    } else {                                // mask compaction
        __shared__ int sc[256];
        int seg = bid - 8464, b = seg >> 1, half = seg & 1;
        const int* m = mask + b * 2048 + half * 1024;
        int v0 = (m[t*4+0] == 0), v1 = (m[t*4+1] == 0);
        int v2 = (m[t*4+2] == 0), v3 = (m[t*4+3] == 0);
        int c = v0 + v1 + v2 + v3;
        sc[t] = c; __syncthreads();
        for (int ofs = 1; ofs < 256; ofs <<= 1) {
            int xx = (t >= ofs) ? sc[t - ofs] : 0;
            __syncthreads(); sc[t] += xx; __syncthreads();
        }
        int pos = sc[t] - c + seg * 1024;
        if (v0) idx[pos++] = t*4+0;
        if (v1) idx[pos++] = t*4+1;
        if (v2) idx[pos++] = t*4+2;
        if (v3) idx[pos++] = t*4+3;
        if (t == 255) cnt[seg] = sc[255];
    }
}

// --------- row translation: compacted key-row -> absolute xb row -------------
__device__ __forceinline__ int map_row(const int* __restrict__ idx,
                                       const int* __restrict__ cnt, int row) {
    int seg = row >> 10, j = row & 1023;
    int src = (j < cnt[seg]) ? idx[(seg << 10) + j] : 0;
    return (seg << 10) + src;
}

// ---------------- shared GEMM core: C[m][n] = sum_k A[m][k]*B[n][k] ----------
// mapA/mapB: translate operand rows through idx/cnt (on-the-fly gather).
__device__ __forceinline__ void gemm_core(const ushort* __restrict__ A,
                                          const ushort* __restrict__ B,
                                          ushort* __restrict__ C,
                                          int N, int K, int mBase, int nBase,
                                          int mapA, int mapB,
                                          const int* __restrict__ idx,
                                          const int* __restrict__ cnt)
{
    __shared__ ushort As[128][32];
    __shared__ ushort Bs[128][32];
    const int tid = threadIdx.x;
    const int lane = tid & 63, wave = tid >> 6;
    const int wm = wave >> 1, wn = wave & 1;
    const int lr = lane & 15, lq = lane >> 4;
    const int sr = lane >> 2;
    const int sc = (lane & 3) * 8;

    // Per-thread staging source pointers (fixed across the K loop).
    const ushort* aptr[2];
    const ushort* bptr[2];
    #pragma unroll
    for (int j = 0; j < 2; ++j) {
        int ra = mBase + wave * 32 + j * 16 + sr;
        int rb = nBase + wave * 32 + j * 16 + sr;
        int sa = mapA ? map_row(idx, cnt, ra) : ra;
        int sb = mapB ? map_row(idx, cnt, rb) : rb;
        aptr[j] = A + (size_t)sa * K + sc;
        bptr[j] = B + (size_t)sb * K + sc;
    }

    f32x4 acc[4][4];
    #pragma unroll
    for (int i = 0; i < 4; ++i)
        #pragma unroll
        for (int j = 0; j < 4; ++j) acc[i][j] = (f32x4){0.f, 0.f, 0.f, 0.f};

    for (int k0 = 0; k0 < K; k0 += 32) {
        __syncthreads();
        #pragma unroll
        for (int j = 0; j < 2; ++j) {
            int rbase = wave * 32 + j * 16;
            async_copy16(&As[rbase][0], aptr[j] + k0);
            async_copy16(&Bs[rbase][0], bptr[j] + k0);
        }
        __syncthreads();
        bf16x8 af[4], bfr[4];
        #pragma unroll
        for (int mi = 0; mi < 4; ++mi) af[mi] = *(const bf16x8*)&As[wm * 64 + mi * 16 + lr][lq * 8];
        #pragma unroll
        for (int ni = 0; ni < 4; ++ni) bfr[ni] = *(const bf16x8*)&Bs[wn * 64 + ni * 16 + lr][lq * 8];
        #pragma unroll
        for (int mi = 0; mi < 4; ++mi)
            #pragma unroll
            for (int ni = 0; ni < 4; ++ni)
                acc[mi][ni] = __builtin_amdgcn_mfma_f32_16x16x32_bf16(af[mi], bfr[ni], acc[mi][ni], 0, 0, 0);
    }
    #pragma unroll
    for (int mi = 0; mi < 4; ++mi)
        #pragma unroll
        for (int ni = 0; ni < 4; ++ni)
            #pragma unroll
            for (int r = 0; r < 4; ++r) {
                int m = mBase + wm * 64 + mi * 16 + lq * 4 + r;
                int n = nBase + wn * 64 + ni * 16 + lr;
                C[(size_t)m * N + n] = f2bf(acc[mi][ni][r]);
            }
}

// fused K' and Vt gemms (z-decode); both skip all-pad 128-bands and gather
// compacted rows from xb via idx on the fly (no separate gather pass).
__global__ __launch_bounds__(256, 2)
void gemm_kv(const ushort* __restrict__ xb, const ushort* __restrict__ Mb,
             ushort* __restrict__ Kc, const ushort* __restrict__ wv,
             ushort* __restrict__ Vtc, const int* __restrict__ idx,
             const int* __restrict__ cnt)
{
    if (blockIdx.z == 0) {
        int mBase = blockIdx.y * 128, nBase = blockIdx.x * 128;
        if ((mBase & 1023) >= cnt[mBase >> 10]) return;
        gemm_core(xb, Mb, Kc, 512, 512, mBase, nBase, 1, 0, idx, cnt);
    } else {
        int mBase = blockIdx.x * 128, nBase = blockIdx.y * 128;
        if ((nBase & 1023) >= cnt[nBase >> 10]) return;
        gemm_core(wv, xb, Vtc, 16384, 512, mBase, nBase, 0, 1, idx, cnt);
    }
}

// ---------------- flash attention over COMPACTED keys (R3/R7-exact) ----------
// Q = xb [B*S][512] bf16. K'c: [16][1024][512]. Vtc: [512][16*1024].
// Grid (32,8,2). 32-key tiles, pair-split PV (mfma 32x32x16), static-max.
// K staged via global_load_lds issued after the mid lgkm-barrier (hides under
// PV, drained one phase later at the top __syncthreads). V reg-staged. XCD
// swizzle + 4-chain QK + setprio. Measured 87 us; LDS-feed of MFMA operands
// is mandatory at this register pressure (R4/R6/R8 all proved direct-L2 worse).
__global__ __launch_bounds__(256, 2)
void attn_kernel(const ushort* __restrict__ Qg, const ushort* __restrict__ Kcg,
                 const ushort* __restrict__ Vtcg, const int* __restrict__ cntg,
                 ushort* __restrict__ Pog, float* __restrict__ Mlg)
{
    const int S = 2048;
    const float SL2E = 0.0637587160f;  // (1/sqrt(512)) * log2(e)

    __shared__ ushort Ks[32][548];
    __shared__ ushort Vs[512][36];
    __shared__ ushort Ps[2][32][36];

    // XCD swizzle: all 32 q-tiles of a segment on one XCD (2 segs/XCD).
    const int lin = blockIdx.x + 32 * blockIdx.y + 256 * blockIdx.z;
    const int seg = (lin & 7) * 2 + (lin >> 8);
    const int qt  = (lin >> 3) & 31;
    const int b = seg >> 1, half = seg & 1;

    const int tid = threadIdx.x, lane = tid & 63, wave = tid >> 6;
    const int lr = lane & 15, lq = lane >> 4;
    const int p = wave >> 1, s = wave & 1;
    const int l32 = lane & 31, lh = lane >> 5;

    const int n = cntg[seg];
    const int ntiles = (n + 31) >> 5;

    const ushort* Qp = Qg + ((size_t)b * S + qt * 64 + wave * 16 + lr) * 512;
    bf16x8 qf[16];
    #pragma unroll
    for (int c = 0; c < 16; ++c) qf[c] = *(const bf16x8*)(Qp + c * 32 + lq * 8);

    f32x16 o[8];
    #pragma unroll
    for (int i = 0; i < 8; ++i)
        #pragma unroll
        for (int r = 0; r < 16; ++r) o[i][r] = 0.f;
    float l_i[4] = {0.f, 0.f, 0.f, 0.f};

    const char* Kseg = (const char*)(Kcg + (size_t)seg * 1024 * 512);
    const char* Vseg = (const char*)Vtcg + (size_t)(seg * 1024) * 2;

    // Prologue: issue K(0) -> Ks (async, 8 rows per wave).
    {
        #pragma unroll
        for (int i = 0; i < 8; ++i) {
            int row = wave * 8 + i;
            async_copy16(&Ks[row][0], Kseg + (size_t)row * 1024 + lane * 16);
        }
    }

    for (int kt = 0; kt < ntiles; ++kt) {
        const int key0 = kt * 32;
        // Top barrier: drains vmcnt(0) -> Ks(kt) landed (issued one full
        // PV-phase ago, except iter 0); Vs/Ps free.
        __syncthreads();
        // V tile kt -> regs; in flight across the QK phase.
        uint4 vreg[8];
        {
            const char* gV = Vseg + (size_t)key0 * 2;
            #pragma unroll
            for (int i = 0; i < 8; ++i) {
                int off = i * 4096 + tid * 16;
                vreg[i] = *(const uint4*)(gV + (size_t)(off >> 6) * 32768 + (off & 63));
            }
        }
        const bool va0 = (key0 + lr) < n;
        const bool va1 = (key0 + 16 + lr) < n;
        // QK^T: 4 independent accumulator chains for MFMA-latency slack.
        f32x4 sA = (f32x4){0.f,0.f,0.f,0.f}, sB = (f32x4){0.f,0.f,0.f,0.f};
        f32x4 sC = (f32x4){0.f,0.f,0.f,0.f}, sD = (f32x4){0.f,0.f,0.f,0.f};
        __builtin_amdgcn_s_setprio(1);
        #pragma unroll
        for (int ks = 0; ks < 16; ks += 2) {
            bf16x8 kf0a = *(const bf16x8*)&Ks[lr][ks * 32 + lq * 8];
            bf16x8 kf1a = *(const bf16x8*)&Ks[16 + lr][ks * 32 + lq * 8];
            bf16x8 kf0b = *(const bf16x8*)&Ks[lr][(ks + 1) * 32 + lq * 8];
            bf16x8 kf1b = *(const bf16x8*)&Ks[16 + lr][(ks + 1) * 32 + lq * 8];
            sA = __builtin_amdgcn_mfma_f32_16x16x32_bf16(qf[ks], kf0a, sA, 0, 0, 0);
            sB = __builtin_amdgcn_mfma_f32_16x16x32_bf16(qf[ks], kf1a, sB, 0, 0, 0);
            sC = __builtin_amdgcn_mfma_f32_16x16x32_bf16(qf[ks + 1], kf0b, sC, 0, 0, 0);
            sD = __builtin_amdgcn_mfma_f32_16x16x32_bf16(qf[ks + 1], kf1b, sD, 0, 0, 0);
        }
        __builtin_amdgcn_s_setprio(0);
        #pragma unroll
        for (int r = 0; r < 4; ++r) {
            float s0 = sA[r] + sC[r], s1 = sB[r] + sD[r];
            float p0 = va0 ? exp2f(fmaf(s0, SL2E, -8.f)) : 0.f;
            float p1 = va1 ? exp2f(fmaf(s1, SL2E, -8.f)) : 0.f;
            l_i[r] += p0 + p1;
            Ps[p][16 * s + lq * 4 + r][lr]      = f2bf(p0);
            Ps[p][16 * s + lq * 4 + r][16 + lr] = f2bf(p1);
        }
        // Commit V tile to LDS (compiler waits vmcnt for vreg only — the K
        // prefetch for kt+1 has not been issued yet, so no false drain).
        #pragma unroll
        for (int i = 0; i < 8; ++i) {
            int off = i * 4096 + tid * 16;
            int row = off >> 6, col = off & 63;
            *(uint4*)((char*)Vs + row * 72 + col) = vreg[i];
        }
        // Mid barrier (lgkm only): Ps + Vs visible; all waves are past their
        // QK reads of Ks -> Ks is dead, safe to overwrite asynchronously.
        lds_barrier();
        // Issue K(kt+1) now; its latency hides under the PV phase below and
        // is drained by the NEXT top __syncthreads().
        if (kt + 1 < ntiles) {
            const char* gK = Kseg + (size_t)(key0 + 32) * 1024;
            #pragma unroll
            for (int i = 0; i < 8; ++i) {
                int row = wave * 8 + i;
                async_copy16(&Ks[row][0], gK + (size_t)row * 1024 + lane * 16);
            }
        }
        bf16x8 pA0 = *(const bf16x8*)&Ps[p][l32][lh * 8];
        bf16x8 pA1 = *(const bf16x8*)&Ps[p][l32][16 + lh * 8];
        __builtin_amdgcn_s_setprio(1);
        #pragma unroll
        for (int dt = 0; dt < 8; ++dt) {
            int d = s * 256 + dt * 32 + l32;
            bf16x8 v0 = *(const bf16x8*)&Vs[d][lh * 8];
            bf16x8 v1 = *(const bf16x8*)&Vs[d][16 + lh * 8];
            o[dt] = __builtin_amdgcn_mfma_f32_32x32x16_bf16(pA0, v0, o[dt], 0, 0, 0);
            o[dt] = __builtin_amdgcn_mfma_f32_32x32x16_bf16(pA1, v1, o[dt], 0, 0, 0);
        }
        __builtin_amdgcn_s_setprio(0);
    }
    #pragma unroll
    for (int r = 0; r < 4; ++r)
        #pragma unroll
        for (int off = 1; off < 16; off <<= 1)
            l_i[r] += __shfl_xor(l_i[r], off, 16);
    const size_t growbase = (size_t)half * 16384 + (size_t)b * S + qt * 64;
    if (lr == 0) {
        #pragma unroll
        for (int r = 0; r < 4; ++r)
            Mlg[growbase + wave * 16 + lq * 4 + r] = l_i[r];
    }
    ushort* Pop = Pog + (growbase + p * 32) * 512;
    #pragma unroll
    for (int dt = 0; dt < 8; ++dt) {
        int ocol = s * 256 + dt * 32 + l32;
        #pragma unroll
        for (int r = 0; r < 16; ++r) {
            int orow = (r & 3) + 8 * (r >> 2) + 4 * lh;
            Pop[(size_t)orow * 512 + ocol] = f2bf(o[dt][r]);
        }
    }
}

// ---------------- combine the two key-halves (16B loads) ----------------
__global__ __launch_bounds__(256)
void combine_kernel(const ushort* __restrict__ Po, const float* __restrict__ Ml,
                    float* __restrict__ out)
{
    int i = (blockIdx.x * 256 + threadIdx.x) * 8;
    int row = i >> 9;
    float l = Ml[row] + Ml[16384 + row];
    float s = l > 0.f ? 1.f / l : 0.f;
    u16x8 p1 = *(const u16x8*)(Po + i);
    u16x8 p2 = *(const u16x8*)(Po + 8388608 + i);
    float4 o1, o2;
    o1.x = (bf2f((ushort)p1[0]) + bf2f((ushort)p2[0])) * s;
    o1.y = (bf2f((ushort)p1[1]) + bf2f((ushort)p2[1])) * s;
    o1.z = (bf2f((ushort)p1[2]) + bf2f((ushort)p2[2])) * s;
    o1.w = (bf2f((ushort)p1[3]) + bf2f((ushort)p2[3])) * s;
    o2.x = (bf2f((ushort)p1[4]) + bf2f((ushort)p2[4])) * s;
    o2.y = (bf2f((ushort)p1[5]) + bf2f((ushort)p2[5])) * s;
    o2.z = (bf2f((ushort)p1[6]) + bf2f((ushort)p2[6])) * s;
    o2.w = (bf2f((ushort)p1[7]) + bf2f((ushort)p2[7])) * s;
    *(float4*)(out + i)     = o1;
    *(float4*)(out + i + 4) = o2;
}

extern "C" void kernel_launch(void* const* d_in, const int* in_sizes, int n_in,
                              void* d_out, int out_size, void* d_ws, size_t ws_size,
                              hipStream_t stream) {
    const float* x  = (const float*)d_in[0];
    // d_in[1] = bias: additive scalar on all logits -> softmax shift-invariant -> no-op
    const int* mask = (const int*)d_in[2];
    const float* Wq = (const float*)d_in[3];
    const float* Wk = (const float*)d_in[4];
    const float* Wv = (const float*)d_in[5];
    float* out = (float*)d_out;

    // Workspace (ushort units). wqT/wkT regions retired (M computed in prep).
    ushort* ws   = (ushort*)d_ws;
    ushort* xb   = ws;
    ushort* wvb  = ws + 8912896;
    ushort* Pob  = ws + 9175040;
    ushort* Mb   = ws + 17563648;
    int*    idxb = (int*)(ws + 17825792);
    ushort* Kc   = ws + 25952256;
    ushort* Vtc  = ws + 34340864;
    float*  Mlb  = (float*)(ws + 42729472);
    int*    cntb = (int*)(ws + 42795008);

    prep_kernel<<<8480, 256, 0, stream>>>(x, Wq, Wk, Wv, mask,
                                          xb, wvb, Mb, idxb, cntb);
    // K'c = gather(xb) M^T  and  Vtc = Wv gather(xb)^T  (fused gather + skip)
    gemm_kv<<<dim3(4, 128, 2), 256, 0, stream>>>(xb, Mb, Kc, wvb, Vtc, idxb, cntb);
    attn_kernel<<<dim3(32, 8, 2), 256, 0, stream>>>(xb, Kc, Vtc, cntb, Pob, Mlb);
    combine_kernel<<<4096, 256, 0, stream>>>(Pob, Mlb, out);
}

// Round 10
// 198.892 us; speedup vs baseline: 1.2611x; 1.1905x over previous
//
#include <hip/hip_runtime.h>

typedef short bf16x8 __attribute__((ext_vector_type(8)));
typedef float f32x4 __attribute__((ext_vector_type(4)));
typedef float f32x16 __attribute__((ext_vector_type(16)));
typedef ushort u16x8 __attribute__((ext_vector_type(8)));

__device__ __forceinline__ ushort f2bf(float f) {
    union { float f; unsigned u; } v; v.f = f;
    unsigned r = (v.u + 0x7fffu + ((v.u >> 16) & 1u)) >> 16;
    return (ushort)r;
}
__device__ __forceinline__ float bf2f(ushort u) {
    union { unsigned u; float f; } v; v.u = ((unsigned)u) << 16;
    return v.f;
}
__device__ __forceinline__ void async_copy16(void* lds, const void* g) {
    __builtin_amdgcn_global_load_lds(
        (const __attribute__((address_space(1))) unsigned*)g,
        (__attribute__((address_space(3))) unsigned*)lds, 16, 0, 0);
}

// ---------------- fused prep: cvt_x | cvt_wT(Wq,Wk) | cvt(Wv) | compact ------
// R7-exact (lesson from R9: register-heavy branches must NOT share a kernel
// with the memory-bound x-convert pass — one VGPR allocation per kernel).
__global__ __launch_bounds__(256)
void prep_kernel(const float* __restrict__ x, const float* __restrict__ Wq,
                 const float* __restrict__ Wk, const float* __restrict__ Wv,
                 const int* __restrict__ mask,
                 ushort* __restrict__ xb, ushort* __restrict__ wqT,
                 ushort* __restrict__ wkT, ushort* __restrict__ wvb,
                 int* __restrict__ idx, int* __restrict__ cnt)
{
    const int bid = blockIdx.x, t = threadIdx.x;
    if (bid < 8192) {                       // x fp32 -> bf16
        int i = (bid * 256 + t) * 4;
        float4 v = *(const float4*)(x + i);
        ushort4 o;
        o.x = f2bf(v.x); o.y = f2bf(v.y); o.z = f2bf(v.z); o.w = f2bf(v.w);
        *(ushort4*)(xb + i) = o;
    } else if (bid < 8320) {                // Wq/Wk transpose-convert
        __shared__ ushort T[64][72];
        int r = bid - 8192;
        const int z = r >> 6; r &= 63;
        const float* in = z ? Wk : Wq;
        ushort* out     = z ? wkT : wqT;
        const int r0 = (r >> 3) * 64, c0 = (r & 7) * 64;
        const int rr = t >> 3, cc8 = (t & 7) * 8;
        #pragma unroll
        for (int pass = 0; pass < 2; ++pass) {
            int rw = rr + pass * 32;
            float4 a = *(const float4*)(in + (size_t)(r0 + rw) * 512 + c0 + cc8);
            float4 bq = *(const float4*)(in + (size_t)(r0 + rw) * 512 + c0 + cc8 + 4);
            T[rw][cc8+0]=f2bf(a.x);  T[rw][cc8+1]=f2bf(a.y);  T[rw][cc8+2]=f2bf(a.z);  T[rw][cc8+3]=f2bf(a.w);
            T[rw][cc8+4]=f2bf(bq.x); T[rw][cc8+5]=f2bf(bq.y); T[rw][cc8+6]=f2bf(bq.z); T[rw][cc8+7]=f2bf(bq.w);
        }
        __syncthreads();
        const int c = t >> 2, seg = (t & 3) * 16;
        ushort tmp[16];
        #pragma unroll
        for (int j = 0; j < 16; ++j) tmp[j] = T[seg + j][c];
        *(uint4*)(out + (size_t)(c0 + c) * 512 + r0 + seg)     = *(uint4*)&tmp[0];
        *(uint4*)(out + (size_t)(c0 + c) * 512 + r0 + seg + 8) = *(uint4*)&tmp[8];
    } else if (bid < 8576) {                // Wv fp32 -> bf16
        int i = ((bid - 8320) * 256 + t) * 4;
        float4 v = *(const float4*)(Wv + i);
        ushort4 o;
        o.x = f2bf(v.x); o.y = f2bf(v.y); o.z = f2bf(v.z); o.w = f2bf(v.w);
        *(ushort4*)(wvb + i) = o;
    } else {                                // mask compaction
        __shared__ int sc[256];
        int seg = bid - 8576, b = seg >> 1, half = seg & 1;
        const int* m = mask + b * 2048 + half * 1024;
        int v0 = (m[t*4+0] == 0), v1 = (m[t*4+1] == 0);
        int v2 = (m[t*4+2] == 0), v3 = (m[t*4+3] == 0);
        int c = v0 + v1 + v2 + v3;
        sc[t] = c; __syncthreads();
        for (int ofs = 1; ofs < 256; ofs <<= 1) {
            int xx = (t >= ofs) ? sc[t - ofs] : 0;
            __syncthreads(); sc[t] += xx; __syncthreads();
        }
        int pos = sc[t] - c + seg * 1024;
        if (v0) idx[pos++] = t*4+0;
        if (v1) idx[pos++] = t*4+1;
        if (v2) idx[pos++] = t*4+2;
        if (v3) idx[pos++] = t*4+3;
        if (t == 255) cnt[seg] = sc[255];
    }
}

// --------- row translation: compacted key-row -> absolute xb row -------------
__device__ __forceinline__ int map_row(const int* __restrict__ idx,
                                       const int* __restrict__ cnt, int row) {
    int seg = row >> 10, j = row & 1023;
    int src = (j < cnt[seg]) ? idx[(seg << 10) + j] : 0;
    return (seg << 10) + src;
}

// ---------------- shared GEMM core: C[m][n] = sum_k A[m][k]*B[n][k] ----------
// mapA/mapB: translate operand rows through idx/cnt (on-the-fly gather).
// vt=1: write V in LANE-MAJOR fragment tiles for attn's global_load_lds:
//   n -> seg=n>>10, key=n&1023 -> kt32=key>>5, g2=(key>>4)&1, k=key&15;
//   m -> db=m>>5, dr=m&31.
//   Fragment (db,g2) is 512 ushorts; lane l of the PV wave needs elements
//   (dr=l&31, k=(l>>5)*8+j) at lane-major offset l*8+j. So:
//   within-frag off = dr*8 + (k>>3)*256 + (k&7).
__device__ __forceinline__ void gemm_core(const ushort* __restrict__ A,
                                          const ushort* __restrict__ B,
                                          ushort* __restrict__ C,
                                          int N, int K, int mBase, int nBase,
                                          int mapA, int mapB,
                                          const int* __restrict__ idx,
                                          const int* __restrict__ cnt,
                                          int vt)
{
    __shared__ ushort As[128][32];
    __shared__ ushort Bs[128][32];
    const int tid = threadIdx.x;
    const int lane = tid & 63, wave = tid >> 6;
    const int wm = wave >> 1, wn = wave & 1;
    const int lr = lane & 15, lq = lane >> 4;
    const int sr = lane >> 2;
    const int sc = (lane & 3) * 8;

    const ushort* aptr[2];
    const ushort* bptr[2];
    #pragma unroll
    for (int j = 0; j < 2; ++j) {
        int ra = mBase + wave * 32 + j * 16 + sr;
        int rb = nBase + wave * 32 + j * 16 + sr;
        int sa = mapA ? map_row(idx, cnt, ra) : ra;
        int sb = mapB ? map_row(idx, cnt, rb) : rb;
        aptr[j] = A + (size_t)sa * K + sc;
        bptr[j] = B + (size_t)sb * K + sc;
    }

    f32x4 acc[4][4];
    #pragma unroll
    for (int i = 0; i < 4; ++i)
        #pragma unroll
        for (int j = 0; j < 4; ++j) acc[i][j] = (f32x4){0.f, 0.f, 0.f, 0.f};

    for (int k0 = 0; k0 < K; k0 += 32) {
        __syncthreads();
        #pragma unroll
        for (int j = 0; j < 2; ++j) {
            int rbase = wave * 32 + j * 16;
            async_copy16(&As[rbase][0], aptr[j] + k0);
            async_copy16(&Bs[rbase][0], bptr[j] + k0);
        }
        __syncthreads();
        bf16x8 af[4], bfr[4];
        #pragma unroll
        for (int mi = 0; mi < 4; ++mi) af[mi] = *(const bf16x8*)&As[wm * 64 + mi * 16 + lr][lq * 8];
        #pragma unroll
        for (int ni = 0; ni < 4; ++ni) bfr[ni] = *(const bf16x8*)&Bs[wn * 64 + ni * 16 + lr][lq * 8];
        #pragma unroll
        for (int mi = 0; mi < 4; ++mi)
            #pragma unroll
            for (int ni = 0; ni < 4; ++ni)
                acc[mi][ni] = __builtin_amdgcn_mfma_f32_16x16x32_bf16(af[mi], bfr[ni], acc[mi][ni], 0, 0, 0);
    }
    #pragma unroll
    for (int mi = 0; mi < 4; ++mi)
        #pragma unroll
        for (int ni = 0; ni < 4; ++ni)
            #pragma unroll
            for (int r = 0; r < 4; ++r) {
                int m = mBase + wm * 64 + mi * 16 + lq * 4 + r;
                int n = nBase + wn * 64 + ni * 16 + lr;
                float val = acc[mi][ni][r];
                if (!vt) {
                    C[(size_t)m * N + n] = f2bf(val);
                } else {
                    int sseg = n >> 10, key = n & 1023;
                    int k = key & 15, g2 = (key >> 4) & 1, kt32 = key >> 5;
                    int db = m >> 5, dr = m & 31;
                    size_t ix = (size_t)sseg * 524288 + (size_t)kt32 * 16384
                              + (size_t)(db * 2 + g2) * 512
                              + (size_t)(k >> 3) * 256 + dr * 8 + (k & 7);
                    C[ix] = f2bf(val);
                }
            }
}

__global__ __launch_bounds__(256, 2)
void gemm_m(const ushort* __restrict__ A, const ushort* __restrict__ B,
            ushort* __restrict__ C) {
    gemm_core(A, B, C, 512, 512, blockIdx.y * 128, blockIdx.x * 128,
              0, 0, nullptr, nullptr, 0);
}

// fused K' and Vt gemms (z-decode); skip all-pad 128-bands; on-the-fly gather.
__global__ __launch_bounds__(256, 2)
void gemm_kv(const ushort* __restrict__ xb, const ushort* __restrict__ Mb,
             ushort* __restrict__ Kc, const ushort* __restrict__ wv,
             ushort* __restrict__ Vtc, const int* __restrict__ idx,
             const int* __restrict__ cnt)
{
    if (blockIdx.z == 0) {
        int mBase = blockIdx.y * 128, nBase = blockIdx.x * 128;
        if ((mBase & 1023) >= cnt[mBase >> 10]) return;
        gemm_core(xb, Mb, Kc, 512, 512, mBase, nBase, 1, 0, idx, cnt, 0);
    } else {
        int mBase = blockIdx.x * 128, nBase = blockIdx.y * 128;
        if ((nBase & 1023) >= cnt[nBase >> 10]) return;
        gemm_core(wv, xb, Vtc, 16384, 512, mBase, nBase, 0, 1, idx, cnt, 1);
    }
}

// ---------------- flash attention over COMPACTED keys ------------------------
// Q = xb (regs). K'c: [16][1024][512] linear, staged to Ks via global_load_lds.
// Vt: lane-major fragment tiles [16][kt32][32 frags][1024B], staged to Vs via
// global_load_lds (no reg round-trip, no ds_writes, conflict-free b128 reads).
// Pipeline: top __syncthreads drains K(kt); issue V(kt) (hides under QK);
// mid __syncthreads drains V(kt); PV; issue K(kt+1) (hides under PV+epilogue,
// drains at next top). V always issues+drains before K issues — no inversion.
__global__ __launch_bounds__(256, 2)
void attn_kernel(const ushort* __restrict__ Qg, const ushort* __restrict__ Kcg,
                 const ushort* __restrict__ Vtcg, const int* __restrict__ cntg,
                 ushort* __restrict__ Pog, float* __restrict__ Mlg)
{
    const int S = 2048;
    const float SL2E = 0.0637587160f;  // (1/sqrt(512)) * log2(e)

    __shared__ ushort Ks[32][548];
    __shared__ ushort Vs[16384];          // one 32-key V tile, fragment order
    __shared__ ushort Ps[2][32][36];

    // XCD swizzle: all 32 q-tiles of a segment on one XCD (2 segs/XCD).
    const int lin = blockIdx.x + 32 * blockIdx.y + 256 * blockIdx.z;
    const int seg = (lin & 7) * 2 + (lin >> 8);
    const int qt  = (lin >> 3) & 31;
    const int b = seg >> 1, half = seg & 1;

    const int tid = threadIdx.x, lane = tid & 63, wave = tid >> 6;
    const int lr = lane & 15, lq = lane >> 4;
    const int p = wave >> 1, s = wave & 1;
    const int l32 = lane & 31, lh = lane >> 5;

    const int n = cntg[seg];
    const int ntiles = (n + 31) >> 5;

    const ushort* Qp = Qg + ((size_t)b * S + qt * 64 + wave * 16 + lr) * 512;
    bf16x8 qf[16];
    #pragma unroll
    for (int c = 0; c < 16; ++c) qf[c] = *(const bf16x8*)(Qp + c * 32 + lq * 8);

    f32x16 o[8];
    #pragma unroll
    for (int i = 0; i < 8; ++i)
        #pragma unroll
        for (int r = 0; r < 16; ++r) o[i][r] = 0.f;
    float l_i[4] = {0.f, 0.f, 0.f, 0.f};

    const char* Kseg = (const char*)(Kcg + (size_t)seg * 1024 * 512);
    const char* Vseg = (const char*)(Vtcg + (size_t)seg * 524288);

    // Prologue: issue K(0) -> Ks (async, 8 rows per wave).
    {
        #pragma unroll
        for (int i = 0; i < 8; ++i) {
            int row = wave * 8 + i;
            async_copy16(&Ks[row][0], Kseg + (size_t)row * 1024 + lane * 16);
        }
    }

    for (int kt = 0; kt < ntiles; ++kt) {
        const int key0 = kt * 32;
        // Top barrier: drains vmcnt -> Ks(kt) landed (in flight since PV of
        // kt-1); all PV(kt-1) reads of Vs done.
        __syncthreads();
        // Issue V(kt) -> Vs (32KB memcpy-style DMA; hides under QK).
        {
            const char* gV = Vseg + (size_t)kt * 32768;
            #pragma unroll
            for (int i = 0; i < 8; ++i) {
                int chunk = i * 4 + wave;
                async_copy16((char*)Vs + chunk * 1024, gV + chunk * 1024 + lane * 16);
            }
        }
        const bool va0 = (key0 + lr) < n;
        const bool va1 = (key0 + 16 + lr) < n;
        // QK^T: 4 independent accumulator chains for MFMA-latency slack.
        f32x4 sA = (f32x4){0.f,0.f,0.f,0.f}, sB = (f32x4){0.f,0.f,0.f,0.f};
        f32x4 sC = (f32x4){0.f,0.f,0.f,0.f}, sD = (f32x4){0.f,0.f,0.f,0.f};
        __builtin_amdgcn_s_setprio(1);
        #pragma unroll
        for (int ks = 0; ks < 16; ks += 2) {
            bf16x8 kf0a = *(const bf16x8*)&Ks[lr][ks * 32 + lq * 8];
            bf16x8 kf1a = *(const bf16x8*)&Ks[16 + lr][ks * 32 + lq * 8];
            bf16x8 kf0b = *(const bf16x8*)&Ks[lr][(ks + 1) * 32 + lq * 8];
            bf16x8 kf1b = *(const bf16x8*)&Ks[16 + lr][(ks + 1) * 32 + lq * 8];
            sA = __builtin_amdgcn_mfma_f32_16x16x32_bf16(qf[ks], kf0a, sA, 0, 0, 0);
            sB = __builtin_amdgcn_mfma_f32_16x16x32_bf16(qf[ks], kf1a, sB, 0, 0, 0);
            sC = __builtin_amdgcn_mfma_f32_16x16x32_bf16(qf[ks + 1], kf0b, sC, 0, 0, 0);
            sD = __builtin_amdgcn_mfma_f32_16x16x32_bf16(qf[ks + 1], kf1b, sD, 0, 0, 0);
        }
        __builtin_amdgcn_s_setprio(0);
        #pragma unroll
        for (int r = 0; r < 4; ++r) {
            float s0 = sA[r] + sC[r], s1 = sB[r] + sD[r];
            float p0 = va0 ? exp2f(fmaf(s0, SL2E, -8.f)) : 0.f;
            float p1 = va1 ? exp2f(fmaf(s1, SL2E, -8.f)) : 0.f;
            l_i[r] += p0 + p1;
            Ps[p][16 * s + lq * 4 + r][lr]      = f2bf(p0);
            Ps[p][16 * s + lq * 4 + r][16 + lr] = f2bf(p1);
        }
        // Mid barrier: drains vmcnt -> Vs(kt) landed (hidden under QK);
        // Ps visible; Ks dead (all QK reads done).
        __syncthreads();
        // Issue K(kt+1): hides under PV + epilogue, drains at next top.
        if (kt + 1 < ntiles) {
            const char* gK = Kseg + (size_t)(key0 + 32) * 1024;
            #pragma unroll
            for (int i = 0; i < 8; ++i) {
                int row = wave * 8 + i;
                async_copy16(&Ks[row][0], gK + (size_t)row * 1024 + lane * 16);
            }
        }
        bf16x8 pA0 = *(const bf16x8*)&Ps[p][l32][lh * 8];
        bf16x8 pA1 = *(const bf16x8*)&Ps[p][l32][16 + lh * 8];
        __builtin_amdgcn_s_setprio(1);
        #pragma unroll
        for (int dt = 0; dt < 8; ++dt) {
            const int db = s * 8 + dt;
            bf16x8 v0 = *(const bf16x8*)((const char*)Vs + (db * 2 + 0) * 1024 + lane * 16);
            bf16x8 v1 = *(const bf16x8*)((const char*)Vs + (db * 2 + 1) * 1024 + lane * 16);
            o[dt] = __builtin_amdgcn_mfma_f32_32x32x16_bf16(pA0, v0, o[dt], 0, 0, 0);
            o[dt] = __builtin_amdgcn_mfma_f32_32x32x16_bf16(pA1, v1, o[dt], 0, 0, 0);
        }
        __builtin_amdgcn_s_setprio(0);
    }
    #pragma unroll
    for (int r = 0; r < 4; ++r)
        #pragma unroll
        for (int off = 1; off < 16; off <<= 1)
            l_i[r] += __shfl_xor(l_i[r], off, 16);
    const size_t growbase = (size_t)half * 16384 + (size_t)b * S + qt * 64;
    if (lr == 0) {
        #pragma unroll
        for (int r = 0; r < 4; ++r)
            Mlg[growbase + wave * 16 + lq * 4 + r] = l_i[r];
    }
    ushort* Pop = Pog + (growbase + p * 32) * 512;
    #pragma unroll
    for (int dt = 0; dt < 8; ++dt) {
        int ocol = s * 256 + dt * 32 + l32;
        #pragma unroll
        for (int r = 0; r < 16; ++r) {
            int orow = (r & 3) + 8 * (r >> 2) + 4 * lh;
            Pop[(size_t)orow * 512 + ocol] = f2bf(o[dt][r]);
        }
    }
}

// ---------------- combine the two key-halves (16B loads) ----------------
__global__ __launch_bounds__(256)
void combine_kernel(const ushort* __restrict__ Po, const float* __restrict__ Ml,
                    float* __restrict__ out)
{
    int i = (blockIdx.x * 256 + threadIdx.x) * 8;
    int row = i >> 9;
    float l = Ml[row] + Ml[16384 + row];
    float s = l > 0.f ? 1.f / l : 0.f;
    u16x8 p1 = *(const u16x8*)(Po + i);
    u16x8 p2 = *(const u16x8*)(Po + 8388608 + i);
    float4 o1, o2;
    o1.x = (bf2f((ushort)p1[0]) + bf2f((ushort)p2[0])) * s;
    o1.y = (bf2f((ushort)p1[1]) + bf2f((ushort)p2[1])) * s;
    o1.z = (bf2f((ushort)p1[2]) + bf2f((ushort)p2[2])) * s;
    o1.w = (bf2f((ushort)p1[3]) + bf2f((ushort)p2[3])) * s;
    o2.x = (bf2f((ushort)p1[4]) + bf2f((ushort)p2[4])) * s;
    o2.y = (bf2f((ushort)p1[5]) + bf2f((ushort)p2[5])) * s;
    o2.z = (bf2f((ushort)p1[6]) + bf2f((ushort)p2[6])) * s;
    o2.w = (bf2f((ushort)p1[7]) + bf2f((ushort)p2[7])) * s;
    *(float4*)(out + i)     = o1;
    *(float4*)(out + i + 4) = o2;
}

extern "C" void kernel_launch(void* const* d_in, const int* in_sizes, int n_in,
                              void* d_out, int out_size, void* d_ws, size_t ws_size,
                              hipStream_t stream) {
    const float* x  = (const float*)d_in[0];
    // d_in[1] = bias: additive scalar on all logits -> softmax shift-invariant -> no-op
    const int* mask = (const int*)d_in[2];
    const float* Wq = (const float*)d_in[3];
    const float* Wk = (const float*)d_in[4];
    const float* Wv = (const float*)d_in[5];
    float* out = (float*)d_out;

    // Workspace (ushort units) — R7 layout; Vtc holds lane-major frag tiles.
    ushort* ws   = (ushort*)d_ws;
    ushort* xb   = ws;
    ushort* wqT  = ws + 8388608;
    ushort* wkT  = wqT + 262144;
    ushort* wvb  = wkT + 262144;
    ushort* Pob  = ws + 9175040;
    ushort* Mb   = ws + 17563648;
    int*    idxb = (int*)(ws + 17825792);
    ushort* Kc   = ws + 25952256;
    ushort* Vtc  = ws + 34340864;
    float*  Mlb  = (float*)(ws + 42729472);
    int*    cntb = (int*)(ws + 42795008);

    prep_kernel<<<8592, 256, 0, stream>>>(x, Wq, Wk, Wv, mask,
                                          xb, wqT, wkT, wvb, idxb, cntb);
    // M = Wq^T Wk
    gemm_m<<<dim3(4, 4), 256, 0, stream>>>(wqT, wkT, Mb);
    // K'c = gather(xb) M^T  and  Vt(lane-major frags) = Wv gather(xb)^T
    gemm_kv<<<dim3(4, 128, 2), 256, 0, stream>>>(xb, Mb, Kc, wvb, Vtc, idxb, cntb);
    attn_kernel<<<dim3(32, 8, 2), 256, 0, stream>>>(xb, Kc, Vtc, cntb, Pob, Mlb);
    combine_kernel<<<4096, 256, 0, stream>>>(Pob, Mlb, out);
}

// Round 13
// 197.778 us; speedup vs baseline: 1.2682x; 1.0056x over previous
//
#include <hip/hip_runtime.h>

typedef short bf16x8 __attribute__((ext_vector_type(8)));
typedef float f32x4 __attribute__((ext_vector_type(4)));
typedef float f32x16 __attribute__((ext_vector_type(16)));
typedef ushort u16x8 __attribute__((ext_vector_type(8)));

__device__ __forceinline__ ushort f2bf(float f) {
    union { float f; unsigned u; } v; v.f = f;
    unsigned r = (v.u + 0x7fffu + ((v.u >> 16) & 1u)) >> 16;
    return (ushort)r;
}
__device__ __forceinline__ float bf2f(ushort u) {
    union { unsigned u; float f; } v; v.u = ((unsigned)u) << 16;
    return v.f;
}
__device__ __forceinline__ void async_copy16(void* lds, const void* g) {
    __builtin_amdgcn_global_load_lds(
        (const __attribute__((address_space(1))) unsigned*)g,
        (__attribute__((address_space(3))) unsigned*)lds, 16, 0, 0);
}

// ------- fused prep: M-gemm (64x64 tiles, low-VGPR) | cvt_x | cvt_Wv | compact
// grid 8528: [0,64) M = Wq^T Wk from raw fp32 (R9-verified math, retiled to
// 64x64 so acc[2][2]=16 VGPR keeps the branch at ~50 regs — R9's failure was
// acc[4][4]+float4[8] ~130 regs throttling the 8192 memory-bound x blocks);
// [64,8256) cvt x; [8256,8512) cvt Wv; [8512,8528) mask compaction.
// M blocks first so they run in the shadow of the memory-bound x pass.
__global__ __launch_bounds__(256)
void prep_kernel(const float* __restrict__ x, const float* __restrict__ Wq,
                 const float* __restrict__ Wk, const float* __restrict__ Wv,
                 const int* __restrict__ mask,
                 ushort* __restrict__ xb, ushort* __restrict__ wvb,
                 ushort* __restrict__ Mb,
                 int* __restrict__ idx, int* __restrict__ cnt)
{
    const int bid = blockIdx.x, t = threadIdx.x;
    if (bid < 64) {                         // M[m][n] = sum_k Wq[k][m] Wk[k][n]
        __shared__ ushort As[64][32];
        __shared__ ushort Bs[64][32];
        const int m0 = (bid >> 3) * 64, n0 = (bid & 7) * 64;
        const int lane = t & 63, wave = t >> 6;
        const int wm = wave >> 1, wn = wave & 1;
        const int lr = lane & 15, lq = lane >> 4;
        const int kk = t >> 3, mm = (t & 7) * 8;

        f32x4 acc[2][2];
        #pragma unroll
        for (int i2 = 0; i2 < 2; ++i2)
            #pragma unroll
            for (int j2 = 0; j2 < 2; ++j2) acc[i2][j2] = (f32x4){0.f,0.f,0.f,0.f};

        for (int k0 = 0; k0 < 512; k0 += 32) {
            float4 qa0 = *(const float4*)(Wq + (size_t)(k0 + kk) * 512 + m0 + mm);
            float4 qa1 = *(const float4*)(Wq + (size_t)(k0 + kk) * 512 + m0 + mm + 4);
            float4 kb0 = *(const float4*)(Wk + (size_t)(k0 + kk) * 512 + n0 + mm);
            float4 kb1 = *(const float4*)(Wk + (size_t)(k0 + kk) * 512 + n0 + mm + 4);
            __syncthreads();   // previous iter's fragment reads done (WAR)
            As[mm + 0][kk] = f2bf(qa0.x); As[mm + 1][kk] = f2bf(qa0.y);
            As[mm + 2][kk] = f2bf(qa0.z); As[mm + 3][kk] = f2bf(qa0.w);
            As[mm + 4][kk] = f2bf(qa1.x); As[mm + 5][kk] = f2bf(qa1.y);
            As[mm + 6][kk] = f2bf(qa1.z); As[mm + 7][kk] = f2bf(qa1.w);
            Bs[mm + 0][kk] = f2bf(kb0.x); Bs[mm + 1][kk] = f2bf(kb0.y);
            Bs[mm + 2][kk] = f2bf(kb0.z); Bs[mm + 3][kk] = f2bf(kb0.w);
            Bs[mm + 4][kk] = f2bf(kb1.x); Bs[mm + 5][kk] = f2bf(kb1.y);
            Bs[mm + 6][kk] = f2bf(kb1.z); Bs[mm + 7][kk] = f2bf(kb1.w);
            __syncthreads();   // staging visible (RAW)
            bf16x8 af[2], bfr[2];
            #pragma unroll
            for (int mi = 0; mi < 2; ++mi) af[mi]  = *(const bf16x8*)&As[wm * 32 + mi * 16 + lr][lq * 8];
            #pragma unroll
            for (int ni = 0; ni < 2; ++ni) bfr[ni] = *(const bf16x8*)&Bs[wn * 32 + ni * 16 + lr][lq * 8];
            #pragma unroll
            for (int mi = 0; mi < 2; ++mi)
                #pragma unroll
                for (int ni = 0; ni < 2; ++ni)
                    acc[mi][ni] = __builtin_amdgcn_mfma_f32_16x16x32_bf16(af[mi], bfr[ni], acc[mi][ni], 0, 0, 0);
        }
        #pragma unroll
        for (int mi = 0; mi < 2; ++mi)
            #pragma unroll
            for (int ni = 0; ni < 2; ++ni)
                #pragma unroll
                for (int r = 0; r < 4; ++r) {
                    int m = m0 + wm * 32 + mi * 16 + lq * 4 + r;
                    int n = n0 + wn * 32 + ni * 16 + lr;
                    Mb[(size_t)m * 512 + n] = f2bf(acc[mi][ni][r]);
                }
    } else if (bid < 8256) {                // x fp32 -> bf16
        int i = ((bid - 64) * 256 + t) * 4;
        float4 v = *(const float4*)(x + i);
        ushort4 o;
        o.x = f2bf(v.x); o.y = f2bf(v.y); o.z = f2bf(v.z); o.w = f2bf(v.w);
        *(ushort4*)(xb + i) = o;
    } else if (bid < 8512) {                // Wv fp32 -> bf16
        int i = ((bid - 8256) * 256 + t) * 4;
        float4 v = *(const float4*)(Wv + i);
        ushort4 o;
        o.x = f2bf(v.x); o.y = f2bf(v.y); o.z = f2bf(v.z); o.w = f2bf(v.w);
        *(ushort4*)(wvb + i) = o;
    } else {                                // mask compaction
        __shared__ int sc[256];
        int seg = bid - 8512, b = seg >> 1, half = seg & 1;
        const int* m = mask + b * 2048 + half * 1024;
        int v0 = (m[t*4+0] == 0), v1 = (m[t*4+1] == 0);
        int v2 = (m[t*4+2] == 0), v3 = (m[t*4+3] == 0);
        int c = v0 + v1 + v2 + v3;
        sc[t] = c; __syncthreads();
        for (int ofs = 1; ofs < 256; ofs <<= 1) {
            int xx = (t >= ofs) ? sc[t - ofs] : 0;
            __syncthreads(); sc[t] += xx; __syncthreads();
        }
        int pos = sc[t] - c + seg * 1024;
        if (v0) idx[pos++] = t*4+0;
        if (v1) idx[pos++] = t*4+1;
        if (v2) idx[pos++] = t*4+2;
        if (v3) idx[pos++] = t*4+3;
        if (t == 255) cnt[seg] = sc[255];
    }
}

// --------- row translation: compacted key-row -> absolute xb row -------------
__device__ __forceinline__ int map_row(const int* __restrict__ idx,
                                       const int* __restrict__ cnt, int row) {
    int seg = row >> 10, j = row & 1023;
    int src = (j < cnt[seg]) ? idx[(seg << 10) + j] : 0;
    return (seg << 10) + src;
}

// ---------------- shared GEMM core: C[m][n] = sum_k A[m][k]*B[n][k] ----------
// mapA/mapB: translate operand rows through idx/cnt (on-the-fly gather).
// vt=1: write V in LANE-MAJOR fragment tiles for attn's global_load_lds
// (verified R10): off = dr*8 + (k>>3)*256 + (k&7) within frag (db*2+g2).
__device__ __forceinline__ void gemm_core(const ushort* __restrict__ A,
                                          const ushort* __restrict__ B,
                                          ushort* __restrict__ C,
                                          int N, int K, int mBase, int nBase,
                                          int mapA, int mapB,
                                          const int* __restrict__ idx,
                                          const int* __restrict__ cnt,
                                          int vt)
{
    __shared__ ushort As[128][32];
    __shared__ ushort Bs[128][32];
    const int tid = threadIdx.x;
    const int lane = tid & 63, wave = tid >> 6;
    const int wm = wave >> 1, wn = wave & 1;
    const int lr = lane & 15, lq = lane >> 4;
    const int sr = lane >> 2;
    const int sc = (lane & 3) * 8;

    const ushort* aptr[2];
    const ushort* bptr[2];
    #pragma unroll
    for (int j = 0; j < 2; ++j) {
        int ra = mBase + wave * 32 + j * 16 + sr;
        int rb = nBase + wave * 32 + j * 16 + sr;
        int sa = mapA ? map_row(idx, cnt, ra) : ra;
        int sb = mapB ? map_row(idx, cnt, rb) : rb;
        aptr[j] = A + (size_t)sa * K + sc;
        bptr[j] = B + (size_t)sb * K + sc;
    }

    f32x4 acc[4][4];
    #pragma unroll
    for (int i = 0; i < 4; ++i)
        #pragma unroll
        for (int j = 0; j < 4; ++j) acc[i][j] = (f32x4){0.f, 0.f, 0.f, 0.f};

    for (int k0 = 0; k0 < K; k0 += 32) {
        __syncthreads();
        #pragma unroll
        for (int j = 0; j < 2; ++j) {
            int rbase = wave * 32 + j * 16;
            async_copy16(&As[rbase][0], aptr[j] + k0);
            async_copy16(&Bs[rbase][0], bptr[j] + k0);
        }
        __syncthreads();
        bf16x8 af[4], bfr[4];
        #pragma unroll
        for (int mi = 0; mi < 4; ++mi) af[mi] = *(const bf16x8*)&As[wm * 64 + mi * 16 + lr][lq * 8];
        #pragma unroll
        for (int ni = 0; ni < 4; ++ni) bfr[ni] = *(const bf16x8*)&Bs[wn * 64 + ni * 16 + lr][lq * 8];
        #pragma unroll
        for (int mi = 0; mi < 4; ++mi)
            #pragma unroll
            for (int ni = 0; ni < 4; ++ni)
                acc[mi][ni] = __builtin_amdgcn_mfma_f32_16x16x32_bf16(af[mi], bfr[ni], acc[mi][ni], 0, 0, 0);
    }
    #pragma unroll
    for (int mi = 0; mi < 4; ++mi)
        #pragma unroll
        for (int ni = 0; ni < 4; ++ni)
            #pragma unroll
            for (int r = 0; r < 4; ++r) {
                int m = mBase + wm * 64 + mi * 16 + lq * 4 + r;
                int n = nBase + wn * 64 + ni * 16 + lr;
                float val = acc[mi][ni][r];
                if (!vt) {
                    C[(size_t)m * N + n] = f2bf(val);
                } else {
                    int sseg = n >> 10, key = n & 1023;
                    int k = key & 15, g2 = (key >> 4) & 1, kt32 = key >> 5;
                    int db = m >> 5, dr = m & 31;
                    size_t ix = (size_t)sseg * 524288 + (size_t)kt32 * 16384
                              + (size_t)(db * 2 + g2) * 512
                              + (size_t)(k >> 3) * 256 + dr * 8 + (k & 7);
                    C[ix] = f2bf(val);
                }
            }
}

// fused K' and Vt gemms (z-decode); skip all-pad 128-bands; on-the-fly gather.
__global__ __launch_bounds__(256, 2)
void gemm_kv(const ushort* __restrict__ xb, const ushort* __restrict__ Mb,
             ushort* __restrict__ Kc, const ushort* __restrict__ wv,
             ushort* __restrict__ Vtc, const int* __restrict__ idx,
             const int* __restrict__ cnt)
{
    if (blockIdx.z == 0) {
        int mBase = blockIdx.y * 128, nBase = blockIdx.x * 128;
        if ((mBase & 1023) >= cnt[mBase >> 10]) return;
        gemm_core(xb, Mb, Kc, 512, 512, mBase, nBase, 1, 0, idx, cnt, 0);
    } else {
        int mBase = blockIdx.x * 128, nBase = blockIdx.y * 128;
        if ((nBase & 1023) >= cnt[nBase >> 10]) return;
        gemm_core(wv, xb, Vtc, 16384, 512, mBase, nBase, 0, 1, idx, cnt, 1);
    }
}

// ---------------- flash attention over COMPACTED keys (R10-exact) ------------
// Q = xb (regs). K'c: [16][1024][512] linear, staged to Ks via global_load_lds.
// Vt: lane-major fragment tiles [16][kt32][32 frags][1024B], staged to Vs via
// global_load_lds (no reg round-trip, no ds_writes, conflict-free b128 reads).
// Pipeline: top __syncthreads drains K(kt); issue V(kt) (hides under QK);
// mid __syncthreads drains V(kt); PV; issue K(kt+1) (hides under PV+epilogue,
// drains at next top). Measured 63.8us standalone, 0 bank conflicts.
__global__ __launch_bounds__(256, 2)
void attn_kernel(const ushort* __restrict__ Qg, const ushort* __restrict__ Kcg,
                 const ushort* __restrict__ Vtcg, const int* __restrict__ cntg,
                 ushort* __restrict__ Pog, float* __restrict__ Mlg)
{
    const int S = 2048;
    const float SL2E = 0.0637587160f;  // (1/sqrt(512)) * log2(e)

    __shared__ ushort Ks[32][548];
    __shared__ ushort Vs[16384];          // one 32-key V tile, fragment order
    __shared__ ushort Ps[2][32][36];

    // XCD swizzle: all 32 q-tiles of a segment on one XCD (2 segs/XCD).
    const int lin = blockIdx.x + 32 * blockIdx.y + 256 * blockIdx.z;
    const int seg = (lin & 7) * 2 + (lin >> 8);
    const int qt  = (lin >> 3) & 31;
    const int b = seg >> 1, half = seg & 1;

    const int tid = threadIdx.x, lane = tid & 63, wave = tid >> 6;
    const int lr = lane & 15, lq = lane >> 4;
    const int p = wave >> 1, s = wave & 1;
    const int l32 = lane & 31, lh = lane >> 5;

    const int n = cntg[seg];
    const int ntiles = (n + 31) >> 5;

    const ushort* Qp = Qg + ((size_t)b * S + qt * 64 + wave * 16 + lr) * 512;
    bf16x8 qf[16];
    #pragma unroll
    for (int c = 0; c < 16; ++c) qf[c] = *(const bf16x8*)(Qp + c * 32 + lq * 8);

    f32x16 o[8];
    #pragma unroll
    for (int i = 0; i < 8; ++i)
        #pragma unroll
        for (int r = 0; r < 16; ++r) o[i][r] = 0.f;
    float l_i[4] = {0.f, 0.f, 0.f, 0.f};

    const char* Kseg = (const char*)(Kcg + (size_t)seg * 1024 * 512);
    const char* Vseg = (const char*)(Vtcg + (size_t)seg * 524288);

    // Prologue: issue K(0) -> Ks (async, 8 rows per wave).
    {
        #pragma unroll
        for (int i = 0; i < 8; ++i) {
            int row = wave * 8 + i;
            async_copy16(&Ks[row][0], Kseg + (size_t)row * 1024 + lane * 16);
        }
    }

    for (int kt = 0; kt < ntiles; ++kt) {
        const int key0 = kt * 32;
        __syncthreads();   // drains vmcnt -> Ks(kt); Vs(kt-1) reads done
        // Issue V(kt) -> Vs (32KB memcpy-style DMA; hides under QK).
        {
            const char* gV = Vseg + (size_t)kt * 32768;
            #pragma unroll
            for (int i = 0; i < 8; ++i) {
                int chunk = i * 4 + wave;
                async_copy16((char*)Vs + chunk * 1024, gV + chunk * 1024 + lane * 16);
            }
        }
        const bool va0 = (key0 + lr) < n;
        const bool va1 = (key0 + 16 + lr) < n;
        // QK^T: 4 independent accumulator chains for MFMA-latency slack.
        f32x4 sA = (f32x4){0.f,0.f,0.f,0.f}, sB = (f32x4){0.f,0.f,0.f,0.f};
        f32x4 sC = (f32x4){0.f,0.f,0.f,0.f}, sD = (f32x4){0.f,0.f,0.f,0.f};
        __builtin_amdgcn_s_setprio(1);
        #pragma unroll
        for (int ks = 0; ks < 16; ks += 2) {
            bf16x8 kf0a = *(const bf16x8*)&Ks[lr][ks * 32 + lq * 8];
            bf16x8 kf1a = *(const bf16x8*)&Ks[16 + lr][ks * 32 + lq * 8];
            bf16x8 kf0b = *(const bf16x8*)&Ks[lr][(ks + 1) * 32 + lq * 8];
            bf16x8 kf1b = *(const bf16x8*)&Ks[16 + lr][(ks + 1) * 32 + lq * 8];
            sA = __builtin_amdgcn_mfma_f32_16x16x32_bf16(qf[ks], kf0a, sA, 0, 0, 0);
            sB = __builtin_amdgcn_mfma_f32_16x16x32_bf16(qf[ks], kf1a, sB, 0, 0, 0);
            sC = __builtin_amdgcn_mfma_f32_16x16x32_bf16(qf[ks + 1], kf0b, sC, 0, 0, 0);
            sD = __builtin_amdgcn_mfma_f32_16x16x32_bf16(qf[ks + 1], kf1b, sD, 0, 0, 0);
        }
        __builtin_amdgcn_s_setprio(0);
        #pragma unroll
        for (int r = 0; r < 4; ++r) {
            float s0 = sA[r] + sC[r], s1 = sB[r] + sD[r];
            float p0 = va0 ? exp2f(fmaf(s0, SL2E, -8.f)) : 0.f;
            float p1 = va1 ? exp2f(fmaf(s1, SL2E, -8.f)) : 0.f;
            l_i[r] += p0 + p1;
            Ps[p][16 * s + lq * 4 + r][lr]      = f2bf(p0);
            Ps[p][16 * s + lq * 4 + r][16 + lr] = f2bf(p1);
        }
        __syncthreads();   // drains vmcnt -> Vs(kt) landed; Ps visible; Ks dead
        // Issue K(kt+1): hides under PV + epilogue, drains at next top.
        if (kt + 1 < ntiles) {
            const char* gK = Kseg + (size_t)(key0 + 32) * 1024;
            #pragma unroll
            for (int i = 0; i < 8; ++i) {
                int row = wave * 8 + i;
                async_copy16(&Ks[row][0], gK + (size_t)row * 1024 + lane * 16);
            }
        }
        bf16x8 pA0 = *(const bf16x8*)&Ps[p][l32][lh * 8];
        bf16x8 pA1 = *(const bf16x8*)&Ps[p][l32][16 + lh * 8];
        __builtin_amdgcn_s_setprio(1);
        #pragma unroll
        for (int dt = 0; dt < 8; ++dt) {
            const int db = s * 8 + dt;
            bf16x8 v0 = *(const bf16x8*)((const char*)Vs + (db * 2 + 0) * 1024 + lane * 16);
            bf16x8 v1 = *(const bf16x8*)((const char*)Vs + (db * 2 + 1) * 1024 + lane * 16);
            o[dt] = __builtin_amdgcn_mfma_f32_32x32x16_bf16(pA0, v0, o[dt], 0, 0, 0);
            o[dt] = __builtin_amdgcn_mfma_f32_32x32x16_bf16(pA1, v1, o[dt], 0, 0, 0);
        }
        __builtin_amdgcn_s_setprio(0);
    }
    #pragma unroll
    for (int r = 0; r < 4; ++r)
        #pragma unroll
        for (int off = 1; off < 16; off <<= 1)
            l_i[r] += __shfl_xor(l_i[r], off, 16);
    const size_t growbase = (size_t)half * 16384 + (size_t)b * S + qt * 64;
    if (lr == 0) {
        #pragma unroll
        for (int r = 0; r < 4; ++r)
            Mlg[growbase + wave * 16 + lq * 4 + r] = l_i[r];
    }
    ushort* Pop = Pog + (growbase + p * 32) * 512;
    #pragma unroll
    for (int dt = 0; dt < 8; ++dt) {
        int ocol = s * 256 + dt * 32 + l32;
        #pragma unroll
        for (int r = 0; r < 16; ++r) {
            int orow = (r & 3) + 8 * (r >> 2) + 4 * lh;
            Pop[(size_t)orow * 512 + ocol] = f2bf(o[dt][r]);
        }
    }
}

// ---------------- combine the two key-halves (16B loads) ----------------
__global__ __launch_bounds__(256)
void combine_kernel(const ushort* __restrict__ Po, const float* __restrict__ Ml,
                    float* __restrict__ out)
{
    int i = (blockIdx.x * 256 + threadIdx.x) * 8;
    int row = i >> 9;
    float l = Ml[row] + Ml[16384 + row];
    float s = l > 0.f ? 1.f / l : 0.f;
    u16x8 p1 = *(const u16x8*)(Po + i);
    u16x8 p2 = *(const u16x8*)(Po + 8388608 + i);
    float4 o1, o2;
    o1.x = (bf2f((ushort)p1[0]) + bf2f((ushort)p2[0])) * s;
    o1.y = (bf2f((ushort)p1[1]) + bf2f((ushort)p2[1])) * s;
    o1.z = (bf2f((ushort)p1[2]) + bf2f((ushort)p2[2])) * s;
    o1.w = (bf2f((ushort)p1[3]) + bf2f((ushort)p2[3])) * s;
    o2.x = (bf2f((ushort)p1[4]) + bf2f((ushort)p2[4])) * s;
    o2.y = (bf2f((ushort)p1[5]) + bf2f((ushort)p2[5])) * s;
    o2.z = (bf2f((ushort)p1[6]) + bf2f((ushort)p2[6])) * s;
    o2.w = (bf2f((ushort)p1[7]) + bf2f((ushort)p2[7])) * s;
    *(float4*)(out + i)     = o1;
    *(float4*)(out + i + 4) = o2;
}

extern "C" void kernel_launch(void* const* d_in, const int* in_sizes, int n_in,
                              void* d_out, int out_size, void* d_ws, size_t ws_size,
                              hipStream_t stream) {
    const float* x  = (const float*)d_in[0];
    // d_in[1] = bias: additive scalar on all logits -> softmax shift-invariant -> no-op
    const int* mask = (const int*)d_in[2];
    const float* Wq = (const float*)d_in[3];
    const float* Wk = (const float*)d_in[4];
    const float* Wv = (const float*)d_in[5];
    float* out = (float*)d_out;

    // Workspace (ushort units) — R10 layout; wqT/wkT slots retired (M computed
    // directly from raw fp32 Wq/Wk inside prep).
    ushort* ws   = (ushort*)d_ws;
    ushort* xb   = ws;
    ushort* wvb  = ws + 8912896;
    ushort* Pob  = ws + 9175040;
    ushort* Mb   = ws + 17563648;
    int*    idxb = (int*)(ws + 17825792);
    ushort* Kc   = ws + 25952256;
    ushort* Vtc  = ws + 34340864;
    float*  Mlb  = (float*)(ws + 42729472);
    int*    cntb = (int*)(ws + 42795008);

    prep_kernel<<<8528, 256, 0, stream>>>(x, Wq, Wk, Wv, mask,
                                          xb, wvb, Mb, idxb, cntb);
    // K'c = gather(xb) M^T  and  Vt(lane-major frags) = Wv gather(xb)^T
    gemm_kv<<<dim3(4, 128, 2), 256, 0, stream>>>(xb, Mb, Kc, wvb, Vtc, idxb, cntb);
    attn_kernel<<<dim3(32, 8, 2), 256, 0, stream>>>(xb, Kc, Vtc, cntb, Pob, Mlb);
    combine_kernel<<<4096, 256, 0, stream>>>(Pob, Mlb, out);
}